// Round 1
// baseline (1185.446 us; speedup 1.0000x reference)
//
#include <hip/hip_runtime.h>

// ---------------------------------------------------------------------------
// GENConv GNN forward: node/edge encode -> 3x (scatter-softmax conv + MLP+BN)
// -> mean pool -> sigmoid dense.  All fp32.
// ---------------------------------------------------------------------------

#define HH 128   // hidden
#define H2 256   // 2*hidden

// ---- node encoder: h = x @ wn + bn   (x: [N,6], wn: [6,128]) ----
__global__ void k_encode(const float* __restrict__ x, const float* __restrict__ wn,
                         const float* __restrict__ bnb, float* __restrict__ h, int n) {
  int c = threadIdx.x & 127;
  int node = blockIdx.x * 2 + (threadIdx.x >> 7);
  if (node >= n) return;
  const float* xr = x + (size_t)node * 6;
  float acc = bnb[c];
#pragma unroll
  for (int k = 0; k < 6; ++k) acc = fmaf(xr[k], wn[k * HH + c], acc);
  h[(size_t)node * HH + c] = acc;
}

// ---- CSR build ----
__global__ void k_hist(const int* __restrict__ dst, int* __restrict__ counts, int E) {
  int e = blockIdx.x * 256 + threadIdx.x;
  if (e < E) atomicAdd(&counts[dst[e]], 1);
}

__global__ void k_scan(const int* __restrict__ counts, int* __restrict__ rowptr, int n) {
  __shared__ int wsum[16];
  __shared__ int carry;
  int t = threadIdx.x;
  int lane = t & 63, w = t >> 6;
  if (t == 0) carry = 0;
  __syncthreads();
  for (int base = 0; base < n; base += 1024) {
    int v = (base + t < n) ? counts[base + t] : 0;
    int x = v;
#pragma unroll
    for (int d = 1; d < 64; d <<= 1) {
      int y = __shfl_up(x, d);
      if (lane >= d) x += y;
    }
    if (lane == 63) wsum[w] = x;
    __syncthreads();
    if (w == 0 && lane < 16) {
      int s = wsum[lane];
#pragma unroll
      for (int d = 1; d < 16; d <<= 1) {
        int y = __shfl_up(s, d);
        if (lane >= d) s += y;
      }
      wsum[lane] = s;
    }
    __syncthreads();
    int waveoff = (w == 0) ? 0 : wsum[w - 1];
    int c0 = carry;
    if (base + t < n) rowptr[base + t] = c0 + waveoff + x - v;
    __syncthreads();
    if (t == 0) carry = c0 + wsum[15];
    __syncthreads();
  }
  if (t == 0) rowptr[n] = carry;
}

__global__ void k_fill(const int* __restrict__ src, const int* __restrict__ dst,
                       const int* __restrict__ rowptr, int* __restrict__ fill,
                       int* __restrict__ ssrc, int* __restrict__ seid, int E) {
  int e = blockIdx.x * 256 + threadIdx.x;
  if (e >= E) return;
  int d = dst[e];
  int pos = rowptr[d] + atomicAdd(&fill[d], 1);
  ssrc[pos] = src[e];
  seid[pos] = e;
}

// ---- GENConv message + softmax aggregation (online softmax over CSR) ----
// one block (128 threads) per dst node; thread = channel
__global__ __launch_bounds__(128) void k_conv(
    const float* __restrict__ h, const float* __restrict__ eattr,
    const float* __restrict__ we, const float* __restrict__ be,
    const int* __restrict__ rowptr, const int* __restrict__ ssrc,
    const int* __restrict__ seid, float* __restrict__ hres, int n) {
  int d = blockIdx.x;
  int c = threadIdx.x;
  float w0 = we[c], w1 = we[HH + c], w2 = we[2 * HH + c], w3 = we[3 * HH + c];
  float bec = be[c];
  int p0 = rowptr[d], p1 = rowptr[d + 1];
  float M = -1e30f, S = 0.f, W = 0.f;
  for (int p = p0; p < p1; ++p) {
    int s = ssrc[p];
    int e = seid[p];
    float4 a = *(const float4*)(eattr + (size_t)e * 4);
    float eac = fmaf(a.x, w0, fmaf(a.y, w1, fmaf(a.z, w2, fmaf(a.w, w3, bec))));
    float m = fmaxf(h[(size_t)s * HH + c] + eac, 0.f) + 1e-7f;
    float newM = fmaxf(M, m);
    float sc = __expf(M - newM);
    float em = __expf(m - newM);
    S = S * sc + em;
    W = W * sc + m * em;
    M = newM;
  }
  float aggr = W / (S + 1e-16f);
  hres[(size_t)d * HH + c] = aggr + h[(size_t)d * HH + c];
}

// ---- mm1: h1 = hres @ w1 + b1, accumulate per-col sum/sumsq for BN ----
// A: [M,128], Wt: [128,256], C: [M,256].  64x64 tile, 4x4 microtile.
__global__ __launch_bounds__(256) void k_mm1(
    const float* __restrict__ A, const float* __restrict__ Wt,
    const float* __restrict__ bias, float* __restrict__ C,
    float* __restrict__ bnsum, float* __restrict__ bnsq, int M) {
  __shared__ float As[64 * 132];
  __shared__ float redS[64], redQ[64];
  int t = threadIdx.x;
  int row0 = blockIdx.x * 64;
#pragma unroll
  for (int i = 0; i < 8; ++i) {
    int fid = t + i * 256;
    int r = fid >> 5, k4 = fid & 31;
    float4 v = make_float4(0.f, 0.f, 0.f, 0.f);
    if (row0 + r < M) v = *(const float4*)(A + (size_t)(row0 + r) * HH + k4 * 4);
    *(float4*)&As[r * 132 + k4 * 4] = v;
  }
  if (t < 64) { redS[t] = 0.f; redQ[t] = 0.f; }
  __syncthreads();
  int cg = t & 15, ng = t >> 4;
  int c0 = blockIdx.y * 64 + cg * 4;
  float acc[4][4];
#pragma unroll
  for (int i = 0; i < 4; ++i) acc[i][0] = acc[i][1] = acc[i][2] = acc[i][3] = 0.f;
#pragma unroll 1
  for (int k = 0; k < 128; k += 4) {
    float4 a[4];
#pragma unroll
    for (int i = 0; i < 4; ++i) a[i] = *(const float4*)&As[(ng * 4 + i) * 132 + k];
#pragma unroll
    for (int kk = 0; kk < 4; ++kk) {
      float4 w = *(const float4*)(Wt + (size_t)(k + kk) * H2 + c0);
#pragma unroll
      for (int i = 0; i < 4; ++i) {
        float av = (&a[i].x)[kk];
        acc[i][0] = fmaf(av, w.x, acc[i][0]);
        acc[i][1] = fmaf(av, w.y, acc[i][1]);
        acc[i][2] = fmaf(av, w.z, acc[i][2]);
        acc[i][3] = fmaf(av, w.w, acc[i][3]);
      }
    }
  }
  float4 bb = *(const float4*)(bias + c0);
  float cs[4] = {0.f, 0.f, 0.f, 0.f}, cq[4] = {0.f, 0.f, 0.f, 0.f};
#pragma unroll
  for (int i = 0; i < 4; ++i) {
    int r = row0 + ng * 4 + i;
    if (r < M) {
      float4 o;
      o.x = acc[i][0] + bb.x;
      o.y = acc[i][1] + bb.y;
      o.z = acc[i][2] + bb.z;
      o.w = acc[i][3] + bb.w;
      *(float4*)(C + (size_t)r * H2 + c0) = o;
      cs[0] += o.x; cs[1] += o.y; cs[2] += o.z; cs[3] += o.w;
      cq[0] += o.x * o.x; cq[1] += o.y * o.y; cq[2] += o.z * o.z; cq[3] += o.w * o.w;
    }
  }
#pragma unroll
  for (int j = 0; j < 4; ++j) {
    atomicAdd(&redS[cg * 4 + j], cs[j]);
    atomicAdd(&redQ[cg * 4 + j], cq[j]);
  }
  __syncthreads();
  if (t < 64) {
    atomicAdd(&bnsum[blockIdx.y * 64 + t], redS[t]);
    atomicAdd(&bnsq[blockIdx.y * 64 + t], redQ[t]);
  }
}

// ---- fold BN stats into per-channel scale/shift ----
__global__ void k_bnfin(const float* __restrict__ bnsum, const float* __restrict__ bnsq,
                        const float* __restrict__ g, const float* __restrict__ bt,
                        float* __restrict__ scale, float* __restrict__ shift, float invN) {
  int c = threadIdx.x;
  float mu = bnsum[c] * invN;
  float var = bnsq[c] * invN - mu * mu;
  float rs = rsqrtf(var + 1e-5f);
  float sc = rs * g[c];
  scale[c] = sc;
  shift[c] = bt[c] - mu * sc;
}

// ---- mm2: h = relu( relu(h1*scale+shift) @ w2 + b2 ) ----
// A: [M,256], Wt: [256,128], C: [M,128]
__global__ __launch_bounds__(256) void k_mm2(
    const float* __restrict__ A, const float* __restrict__ Wt,
    const float* __restrict__ bias, const float* __restrict__ scale,
    const float* __restrict__ shift, float* __restrict__ C, int M) {
  __shared__ float As[64 * 132];
  int t = threadIdx.x;
  int row0 = blockIdx.x * 64;
  int cg = t & 15, ng = t >> 4;
  int c0 = blockIdx.y * 64 + cg * 4;
  float acc[4][4];
#pragma unroll
  for (int i = 0; i < 4; ++i) acc[i][0] = acc[i][1] = acc[i][2] = acc[i][3] = 0.f;
  for (int kc = 0; kc < H2; kc += 128) {
    __syncthreads();
#pragma unroll
    for (int i = 0; i < 8; ++i) {
      int fid = t + i * 256;
      int r = fid >> 5, k4 = fid & 31;
      float4 v = make_float4(0.f, 0.f, 0.f, 0.f);
      if (row0 + r < M) {
        v = *(const float4*)(A + (size_t)(row0 + r) * H2 + kc + k4 * 4);
        float4 sc = *(const float4*)(scale + kc + k4 * 4);
        float4 sh = *(const float4*)(shift + kc + k4 * 4);
        v.x = fmaxf(fmaf(v.x, sc.x, sh.x), 0.f);
        v.y = fmaxf(fmaf(v.y, sc.y, sh.y), 0.f);
        v.z = fmaxf(fmaf(v.z, sc.z, sh.z), 0.f);
        v.w = fmaxf(fmaf(v.w, sc.w, sh.w), 0.f);
      }
      *(float4*)&As[r * 132 + k4 * 4] = v;
    }
    __syncthreads();
#pragma unroll 1
    for (int k = 0; k < 128; k += 4) {
      float4 a[4];
#pragma unroll
      for (int i = 0; i < 4; ++i) a[i] = *(const float4*)&As[(ng * 4 + i) * 132 + k];
#pragma unroll
      for (int kk = 0; kk < 4; ++kk) {
        float4 w = *(const float4*)(Wt + (size_t)(kc + k + kk) * HH + c0);
#pragma unroll
        for (int i = 0; i < 4; ++i) {
          float av = (&a[i].x)[kk];
          acc[i][0] = fmaf(av, w.x, acc[i][0]);
          acc[i][1] = fmaf(av, w.y, acc[i][1]);
          acc[i][2] = fmaf(av, w.z, acc[i][2]);
          acc[i][3] = fmaf(av, w.w, acc[i][3]);
        }
      }
    }
  }
  float4 bb = *(const float4*)(bias + c0);
#pragma unroll
  for (int i = 0; i < 4; ++i) {
    int r = row0 + ng * 4 + i;
    if (r < M) {
      float4 o;
      o.x = fmaxf(acc[i][0] + bb.x, 0.f);
      o.y = fmaxf(acc[i][1] + bb.y, 0.f);
      o.z = fmaxf(acc[i][2] + bb.z, 0.f);
      o.w = fmaxf(acc[i][3] + bb.w, 0.f);
      *(float4*)(C + (size_t)r * HH + c0) = o;
    }
  }
}

// ---- graph node counts ----
__global__ void k_cnt(const int* __restrict__ batch, float* __restrict__ cntf, int n) {
  int i = blockIdx.x * 256 + threadIdx.x;
  if (i < n) atomicAdd(&cntf[batch[i]], 1.f);
}

// ---- mean-pool partial sums (batch is sorted -> run-length accumulate) ----
__global__ __launch_bounds__(128) void k_pool(const float* __restrict__ h,
                                              const int* __restrict__ batch,
                                              float* __restrict__ pool, int n) {
  int c = threadIdx.x;
  int n0 = blockIdx.x * 64;
  int nend = min(n0 + 64, n);
  float acc = 0.f;
  int gprev = batch[n0];
  for (int i = n0; i < nend; ++i) {
    int g = batch[i];
    if (g != gprev) {
      atomicAdd(&pool[(size_t)gprev * HH + c], acc);
      acc = 0.f;
      gprev = g;
    }
    acc += h[(size_t)i * HH + c];
  }
  atomicAdd(&pool[(size_t)gprev * HH + c], acc);
}

// ---- final: sigmoid(mean_pool @ wd + bd) ----
__global__ __launch_bounds__(64) void k_final(const float* __restrict__ pool,
                                              const float* __restrict__ cntf,
                                              const float* __restrict__ wd,
                                              const float* __restrict__ bd,
                                              float* __restrict__ out) {
  int g = blockIdx.x;
  int t = threadIdx.x;
  float inv = 1.f / fmaxf(cntf[g], 1.f);
  float v = pool[(size_t)g * HH + t] * inv * wd[t] +
            pool[(size_t)g * HH + 64 + t] * inv * wd[64 + t];
#pragma unroll
  for (int d = 32; d; d >>= 1) v += __shfl_down(v, d);
  if (t == 0) out[g] = 1.f / (1.f + __expf(-(v + bd[0])));
}

// ---------------------------------------------------------------------------
extern "C" void kernel_launch(void* const* d_in, const int* in_sizes, int n_in,
                              void* d_out, int out_size, void* d_ws, size_t ws_size,
                              hipStream_t stream) {
  const float* x        = (const float*)d_in[0];
  const float* eattr    = (const float*)d_in[1];
  const int*   eidx     = (const int*)d_in[2];
  const int*   batch    = (const int*)d_in[3];
  const float* wn       = (const float*)d_in[4];
  const float* bnb      = (const float*)d_in[5];
  const float* we       = (const float*)d_in[6];
  const float* be       = (const float*)d_in[7];
  const float* cw1      = (const float*)d_in[8];
  const float* cb1      = (const float*)d_in[9];
  const float* cg       = (const float*)d_in[10];
  const float* cbt      = (const float*)d_in[11];
  const float* cw2      = (const float*)d_in[12];
  const float* cb2      = (const float*)d_in[13];
  const float* wd       = (const float*)d_in[14];
  const float* bd       = (const float*)d_in[15];
  float* out = (float*)d_out;

  const int N = in_sizes[0] / 6;
  const int E = in_sizes[1] / 4;
  const int G = out_size;

  const int* src = eidx;
  const int* dst = eidx + E;

  char* ws = (char*)d_ws;
  size_t off = 0;
  auto alloc = [&](size_t bytes) -> char* {
    char* p = ws + off;
    off = (off + bytes + 255) & ~(size_t)255;
    return p;
  };
  float* h      = (float*)alloc((size_t)N * HH * 4);
  float* hres   = (float*)alloc((size_t)N * HH * 4);
  float* h1     = (float*)alloc((size_t)N * H2 * 4);
  int*   rowptr = (int*)alloc((size_t)(N + 1) * 4);
  int*   counts = (int*)alloc((size_t)N * 4);
  int*   fill   = (int*)alloc((size_t)N * 4);
  int*   ssrc   = (int*)alloc((size_t)E * 4);
  int*   seid   = (int*)alloc((size_t)E * 4);
  float* stats  = (float*)alloc(512 * 4);   // bnsum[256] + bnsq[256]
  float* bnsc   = (float*)alloc(256 * 4);
  float* bnsh   = (float*)alloc(256 * 4);
  float* pool   = (float*)alloc((size_t)G * HH * 4);
  float* cntf   = (float*)alloc((size_t)G * 4);

  (void)ws_size; (void)n_in;

  hipMemsetAsync(counts, 0, (size_t)N * 4, stream);
  hipMemsetAsync(fill, 0, (size_t)N * 4, stream);
  hipMemsetAsync(pool, 0, (size_t)G * HH * 4, stream);
  hipMemsetAsync(cntf, 0, (size_t)G * 4, stream);

  k_encode<<<(N + 1) / 2, 256, 0, stream>>>(x, wn, bnb, h, N);
  k_hist<<<(E + 255) / 256, 256, 0, stream>>>(dst, counts, E);
  k_scan<<<1, 1024, 0, stream>>>(counts, rowptr, N);
  k_fill<<<(E + 255) / 256, 256, 0, stream>>>(src, dst, rowptr, fill, ssrc, seid, E);

  int mtiles = (N + 63) / 64;
  for (int layer = 0; layer < 3; ++layer) {
    const float* w1 = cw1 + (size_t)layer * HH * H2;
    const float* b1 = cb1 + (size_t)layer * H2;
    const float* g_ = cg + (size_t)layer * H2;
    const float* bt = cbt + (size_t)layer * H2;
    const float* w2 = cw2 + (size_t)layer * H2 * HH;
    const float* b2 = cb2 + (size_t)layer * HH;

    k_conv<<<N, 128, 0, stream>>>(h, eattr, we, be, rowptr, ssrc, seid, hres, N);
    hipMemsetAsync(stats, 0, 512 * 4, stream);
    k_mm1<<<dim3(mtiles, 4), 256, 0, stream>>>(hres, w1, b1, h1, stats, stats + 256, N);
    k_bnfin<<<1, 256, 0, stream>>>(stats, stats + 256, g_, bt, bnsc, bnsh, 1.f / (float)N);
    k_mm2<<<dim3(mtiles, 2), 256, 0, stream>>>(h1, w2, b2, bnsc, bnsh, h, N);
  }

  k_cnt<<<(N + 255) / 256, 256, 0, stream>>>(batch, cntf, N);
  k_pool<<<mtiles, 128, 0, stream>>>(h, batch, pool, N);
  k_final<<<G, 64, 0, stream>>>(pool, cntf, wd, bd, out);
}

// Round 2
// 762.376 us; speedup vs baseline: 1.5549x; 1.5549x over previous
//
#include <hip/hip_runtime.h>

// ---------------------------------------------------------------------------
// GENConv GNN forward: node/edge encode -> 3x (scatter-softmax conv + MLP+BN)
// -> mean pool -> sigmoid dense.
// Round 1: MLP matmuls moved to bf16 MFMA (16x16x32), fragment-major LDS.
// ---------------------------------------------------------------------------

#define HH 128   // hidden
#define H2 256   // 2*hidden

typedef __attribute__((ext_vector_type(8))) short short8v;
typedef __attribute__((ext_vector_type(4))) float f32x4;

__device__ __forceinline__ short f2bf(float f) {
  union { float f; unsigned u; } v; v.f = f;
  unsigned r = v.u + 0x7fff + ((v.u >> 16) & 1);  // round-to-nearest-even
  return (short)(r >> 16);
}

// ---- node encoder: h = x @ wn + bn   (x: [N,6], wn: [6,128]) ----
__global__ void k_encode(const float* __restrict__ x, const float* __restrict__ wn,
                         const float* __restrict__ bnb, float* __restrict__ h, int n) {
  int c = threadIdx.x & 127;
  int node = blockIdx.x * 2 + (threadIdx.x >> 7);
  if (node >= n) return;
  const float* xr = x + (size_t)node * 6;
  float acc = bnb[c];
#pragma unroll
  for (int k = 0; k < 6; ++k) acc = fmaf(xr[k], wn[k * HH + c], acc);
  h[(size_t)node * HH + c] = acc;
}

// ---- CSR build ----
__global__ void k_hist(const int* __restrict__ dst, int* __restrict__ counts, int E) {
  int e = blockIdx.x * 256 + threadIdx.x;
  if (e < E) atomicAdd(&counts[dst[e]], 1);
}

__global__ void k_scan(const int* __restrict__ counts, int* __restrict__ rowptr, int n) {
  __shared__ int wsum[16];
  __shared__ int carry;
  int t = threadIdx.x;
  int lane = t & 63, w = t >> 6;
  if (t == 0) carry = 0;
  __syncthreads();
  for (int base = 0; base < n; base += 1024) {
    int v = (base + t < n) ? counts[base + t] : 0;
    int x = v;
#pragma unroll
    for (int d = 1; d < 64; d <<= 1) {
      int y = __shfl_up(x, d);
      if (lane >= d) x += y;
    }
    if (lane == 63) wsum[w] = x;
    __syncthreads();
    if (w == 0 && lane < 16) {
      int s = wsum[lane];
#pragma unroll
      for (int d = 1; d < 16; d <<= 1) {
        int y = __shfl_up(s, d);
        if (lane >= d) s += y;
      }
      wsum[lane] = s;
    }
    __syncthreads();
    int waveoff = (w == 0) ? 0 : wsum[w - 1];
    int c0 = carry;
    if (base + t < n) rowptr[base + t] = c0 + waveoff + x - v;
    __syncthreads();
    if (t == 0) carry = c0 + wsum[15];
    __syncthreads();
  }
  if (t == 0) rowptr[n] = carry;
}

__global__ void k_fill(const int* __restrict__ src, const int* __restrict__ dst,
                       const int* __restrict__ rowptr, int* __restrict__ fill,
                       int* __restrict__ ssrc, int* __restrict__ seid, int E) {
  int e = blockIdx.x * 256 + threadIdx.x;
  if (e >= E) return;
  int d = dst[e];
  int pos = rowptr[d] + atomicAdd(&fill[d], 1);
  ssrc[pos] = src[e];
  seid[pos] = e;
}

// ---- GENConv message + softmax aggregation (online softmax over CSR) ----
__global__ __launch_bounds__(128) void k_conv(
    const float* __restrict__ h, const float* __restrict__ eattr,
    const float* __restrict__ we, const float* __restrict__ be,
    const int* __restrict__ rowptr, const int* __restrict__ ssrc,
    const int* __restrict__ seid, float* __restrict__ hres, int n) {
  int d = blockIdx.x;
  int c = threadIdx.x;
  float w0 = we[c], w1 = we[HH + c], w2 = we[2 * HH + c], w3 = we[3 * HH + c];
  float bec = be[c];
  int p0 = rowptr[d], p1 = rowptr[d + 1];
  float M = -1e30f, S = 0.f, W = 0.f;
  for (int p = p0; p < p1; ++p) {
    int s = ssrc[p];
    int e = seid[p];
    float4 a = *(const float4*)(eattr + (size_t)e * 4);
    float eac = fmaf(a.x, w0, fmaf(a.y, w1, fmaf(a.z, w2, fmaf(a.w, w3, bec))));
    float m = fmaxf(h[(size_t)s * HH + c] + eac, 0.f) + 1e-7f;
    float newM = fmaxf(M, m);
    float sc = __expf(M - newM);
    float em = __expf(m - newM);
    S = S * sc + em;
    W = W * sc + m * em;
    M = newM;
  }
  float aggr = W / (S + 1e-16f);
  hres[(size_t)d * HH + c] = aggr + h[(size_t)d * HH + c];
}

// ---- weight pre-convert: fp32 [K][Ncols] -> bf16 fragment-major ----
// layout: [ty][kc][ (((wc*4+n)*4+ksl)*64 + lhi*16+l15)*8 + j ]  (16384 per (ty,kc))
// where col = ty*128 + wc*64 + n*16 + l15, k = kc*128 + ksl*32 + lhi*8 + j
__global__ void k_wconv(const float* __restrict__ W, short* __restrict__ out,
                        int logn, int K) {
  int layer = blockIdx.y;
  int total = K << logn;
  int e = blockIdx.x * 256 + threadIdx.x;
  if (e >= total) return;
  const float* Wl = W + (size_t)layer * total;
  short* ol = out + (size_t)layer * total;
  int k = e >> logn, col = e & ((1 << logn) - 1);
  int ty = col >> 7, colL = col & 127;
  int wc = colL >> 6, n = (colL >> 4) & 3, l15 = colL & 15;
  int kc = k >> 7, kl = k & 127;
  int ksl = kl >> 5, lhi = (kl >> 3) & 3, j = kl & 7;
  int KC = K >> 7;
  size_t idx = (size_t)(ty * KC + kc) * 16384 +
               ((((wc * 4 + n) * 4 + ksl) * 64 + lhi * 16 + l15) * 8 + j);
  ol[idx] = f2bf(Wl[e]);
}

// ---- mm1 (MFMA): h1 = hres @ w1 + b1, fp32 out, BN sum/sumsq ----
// A: [M,128] fp32, Bf: fragment-major bf16 (2 tiles of 16384), C: [M,256]
__global__ __launch_bounds__(256) void k_mm1f(
    const float* __restrict__ A, const short* __restrict__ Bf,
    const float* __restrict__ bias, float* __restrict__ C,
    float* __restrict__ bnsum, float* __restrict__ bnsq, int M) {
  __shared__ short As[16384];
  __shared__ short Bs[16384];
  int t = threadIdx.x;
  int row0 = blockIdx.x * 128;
  int ty = blockIdx.y;
  // stage B (pure 16B copy, already fragment-major)
  {
    const short8v* srcB = (const short8v*)(Bf + (size_t)ty * 16384);
    short8v* dstB = (short8v*)Bs;
#pragma unroll
    for (int i = 0; i < 8; ++i) dstB[i * 256 + t] = srcB[i * 256 + t];
  }
  // stage A: load fp32, cvt bf16, write fragment-major
  {
    int l15 = t & 15, k8 = t >> 4;
    int ksl = k8 >> 2, lhi = k8 & 3;
    int laneF = lhi * 16 + l15;
#pragma unroll
    for (int i = 0; i < 8; ++i) {
      int grow = row0 + i * 16 + l15;
      float4 v0 = make_float4(0.f, 0.f, 0.f, 0.f), v1 = v0;
      if (grow < M) {
        const float* p = A + (size_t)grow * HH + k8 * 8;
        v0 = *(const float4*)p;
        v1 = *(const float4*)(p + 4);
      }
      short8v s;
      s[0] = f2bf(v0.x); s[1] = f2bf(v0.y); s[2] = f2bf(v0.z); s[3] = f2bf(v0.w);
      s[4] = f2bf(v1.x); s[5] = f2bf(v1.y); s[6] = f2bf(v1.z); s[7] = f2bf(v1.w);
      *(short8v*)&As[((i * 4 + ksl) * 64 + laneF) * 8] = s;
    }
  }
  __syncthreads();
  int lane = t & 63, w = t >> 6;
  int wr = w >> 1, wc = w & 1;
  f32x4 acc[4][4];
#pragma unroll
  for (int m = 0; m < 4; ++m)
#pragma unroll
    for (int n = 0; n < 4; ++n) acc[m][n] = (f32x4){0.f, 0.f, 0.f, 0.f};
#pragma unroll
  for (int ksl = 0; ksl < 4; ++ksl) {
    short8v a[4], b[4];
#pragma unroll
    for (int m = 0; m < 4; ++m)
      a[m] = *(const short8v*)&As[(((wr * 4 + m) * 4 + ksl) * 64 + lane) * 8];
#pragma unroll
    for (int n = 0; n < 4; ++n)
      b[n] = *(const short8v*)&Bs[(((wc * 4 + n) * 4 + ksl) * 64 + lane) * 8];
#pragma unroll
    for (int m = 0; m < 4; ++m)
#pragma unroll
      for (int n = 0; n < 4; ++n)
        acc[m][n] = __builtin_amdgcn_mfma_f32_16x16x32_bf16(a[m], b[n], acc[m][n], 0, 0, 0);
  }
  __syncthreads();
  // reuse As as BN reduction buffer: [0..127]=sum, [128..255]=sumsq
  float* red = (float*)As;
  red[t < 256 ? t : 0] = 0.f;
  __syncthreads();
  int l15c = lane & 15, rq = lane >> 4;
#pragma unroll
  for (int n = 0; n < 4; ++n) {
    int colL = wc * 64 + n * 16 + l15c;
    float bb = bias[ty * 128 + colL];
    float cs = 0.f, cq = 0.f;
#pragma unroll
    for (int m = 0; m < 4; ++m) {
      int rbase = row0 + wr * 64 + m * 16 + rq * 4;
#pragma unroll
      for (int r = 0; r < 4; ++r) {
        int row = rbase + r;
        if (row < M) {
          float o = acc[m][n][r] + bb;
          C[(size_t)row * H2 + ty * 128 + colL] = o;
          cs += o; cq += o * o;
        }
      }
    }
    atomicAdd(&red[colL], cs);
    atomicAdd(&red[128 + colL], cq);
  }
  __syncthreads();
  if (t < 128) {
    atomicAdd(&bnsum[ty * 128 + t], red[t]);
    atomicAdd(&bnsq[ty * 128 + t], red[128 + t]);
  }
}

// ---- fold BN stats into per-channel scale/shift ----
__global__ void k_bnfin(const float* __restrict__ bnsum, const float* __restrict__ bnsq,
                        const float* __restrict__ g, const float* __restrict__ bt,
                        float* __restrict__ scale, float* __restrict__ shift, float invN) {
  int c = threadIdx.x;
  float mu = bnsum[c] * invN;
  float var = bnsq[c] * invN - mu * mu;
  float rs = rsqrtf(var + 1e-5f);
  float sc = rs * g[c];
  scale[c] = sc;
  shift[c] = bt[c] - mu * sc;
}

// ---- mm2 (MFMA): h = relu( relu(h1*scale+shift) @ w2 + b2 ) ----
// A: [M,256] fp32, Bf: fragment-major bf16 (kc chunks of 16384), C: [M,128]
__global__ __launch_bounds__(256) void k_mm2f(
    const float* __restrict__ A, const short* __restrict__ Bf,
    const float* __restrict__ bias, const float* __restrict__ scale,
    const float* __restrict__ shift, float* __restrict__ C, int M) {
  __shared__ short As[16384];
  __shared__ short Bs[16384];
  int t = threadIdx.x;
  int row0 = blockIdx.x * 128;
  int lane = t & 63, w = t >> 6;
  int wr = w >> 1, wc = w & 1;
  int l15 = t & 15, k8 = t >> 4;
  int ksl0 = k8 >> 2, lhi = k8 & 3;
  int laneF = lhi * 16 + l15;
  f32x4 acc[4][4];
#pragma unroll
  for (int m = 0; m < 4; ++m)
#pragma unroll
    for (int n = 0; n < 4; ++n) acc[m][n] = (f32x4){0.f, 0.f, 0.f, 0.f};
#pragma unroll 1
  for (int kc = 0; kc < 2; ++kc) {
    if (kc) __syncthreads();
    // stage B
    {
      const short8v* srcB = (const short8v*)(Bf + (size_t)kc * 16384);
      short8v* dstB = (short8v*)Bs;
#pragma unroll
      for (int i = 0; i < 8; ++i) dstB[i * 256 + t] = srcB[i * 256 + t];
    }
    // stage A with fused BN scale/shift + relu
    {
      float4 sc0 = *(const float4*)(scale + kc * 128 + k8 * 8);
      float4 sc1 = *(const float4*)(scale + kc * 128 + k8 * 8 + 4);
      float4 sh0 = *(const float4*)(shift + kc * 128 + k8 * 8);
      float4 sh1 = *(const float4*)(shift + kc * 128 + k8 * 8 + 4);
#pragma unroll
      for (int i = 0; i < 8; ++i) {
        int grow = row0 + i * 16 + l15;
        float4 v0 = make_float4(0.f, 0.f, 0.f, 0.f), v1 = v0;
        if (grow < M) {
          const float* p = A + (size_t)grow * H2 + kc * 128 + k8 * 8;
          v0 = *(const float4*)p;
          v1 = *(const float4*)(p + 4);
          v0.x = fmaxf(fmaf(v0.x, sc0.x, sh0.x), 0.f);
          v0.y = fmaxf(fmaf(v0.y, sc0.y, sh0.y), 0.f);
          v0.z = fmaxf(fmaf(v0.z, sc0.z, sh0.z), 0.f);
          v0.w = fmaxf(fmaf(v0.w, sc0.w, sh0.w), 0.f);
          v1.x = fmaxf(fmaf(v1.x, sc1.x, sh1.x), 0.f);
          v1.y = fmaxf(fmaf(v1.y, sc1.y, sh1.y), 0.f);
          v1.z = fmaxf(fmaf(v1.z, sc1.z, sh1.z), 0.f);
          v1.w = fmaxf(fmaf(v1.w, sc1.w, sh1.w), 0.f);
        }
        short8v s;
        s[0] = f2bf(v0.x); s[1] = f2bf(v0.y); s[2] = f2bf(v0.z); s[3] = f2bf(v0.w);
        s[4] = f2bf(v1.x); s[5] = f2bf(v1.y); s[6] = f2bf(v1.z); s[7] = f2bf(v1.w);
        *(short8v*)&As[((i * 4 + ksl0) * 64 + laneF) * 8] = s;
      }
    }
    __syncthreads();
#pragma unroll
    for (int ksl = 0; ksl < 4; ++ksl) {
      short8v a[4], b[4];
#pragma unroll
      for (int m = 0; m < 4; ++m)
        a[m] = *(const short8v*)&As[(((wr * 4 + m) * 4 + ksl) * 64 + lane) * 8];
#pragma unroll
      for (int n = 0; n < 4; ++n)
        b[n] = *(const short8v*)&Bs[(((wc * 4 + n) * 4 + ksl) * 64 + lane) * 8];
#pragma unroll
      for (int m = 0; m < 4; ++m)
#pragma unroll
        for (int n = 0; n < 4; ++n)
          acc[m][n] = __builtin_amdgcn_mfma_f32_16x16x32_bf16(a[m], b[n], acc[m][n], 0, 0, 0);
    }
  }
  int l15c = lane & 15, rq = lane >> 4;
#pragma unroll
  for (int n = 0; n < 4; ++n) {
    int colL = wc * 64 + n * 16 + l15c;
    float bb = bias[colL];
#pragma unroll
    for (int m = 0; m < 4; ++m) {
      int rbase = row0 + wr * 64 + m * 16 + rq * 4;
#pragma unroll
      for (int r = 0; r < 4; ++r) {
        int row = rbase + r;
        if (row < M)
          C[(size_t)row * HH + colL] = fmaxf(acc[m][n][r] + bb, 0.f);
      }
    }
  }
}

// ---- graph node counts ----
__global__ void k_cnt(const int* __restrict__ batch, float* __restrict__ cntf, int n) {
  int i = blockIdx.x * 256 + threadIdx.x;
  if (i < n) atomicAdd(&cntf[batch[i]], 1.f);
}

// ---- mean-pool partial sums (batch sorted -> run-length accumulate) ----
__global__ __launch_bounds__(128) void k_pool(const float* __restrict__ h,
                                              const int* __restrict__ batch,
                                              float* __restrict__ pool, int n) {
  int c = threadIdx.x;
  int n0 = blockIdx.x * 64;
  int nend = min(n0 + 64, n);
  float acc = 0.f;
  int gprev = batch[n0];
  for (int i = n0; i < nend; ++i) {
    int g = batch[i];
    if (g != gprev) {
      atomicAdd(&pool[(size_t)gprev * HH + c], acc);
      acc = 0.f;
      gprev = g;
    }
    acc += h[(size_t)i * HH + c];
  }
  atomicAdd(&pool[(size_t)gprev * HH + c], acc);
}

// ---- final: sigmoid(mean_pool @ wd + bd) ----
__global__ __launch_bounds__(64) void k_final(const float* __restrict__ pool,
                                              const float* __restrict__ cntf,
                                              const float* __restrict__ wd,
                                              const float* __restrict__ bd,
                                              float* __restrict__ out) {
  int g = blockIdx.x;
  int t = threadIdx.x;
  float inv = 1.f / fmaxf(cntf[g], 1.f);
  float v = pool[(size_t)g * HH + t] * inv * wd[t] +
            pool[(size_t)g * HH + 64 + t] * inv * wd[64 + t];
#pragma unroll
  for (int d = 32; d; d >>= 1) v += __shfl_down(v, d);
  if (t == 0) out[g] = 1.f / (1.f + __expf(-(v + bd[0])));
}

// ---------------------------------------------------------------------------
extern "C" void kernel_launch(void* const* d_in, const int* in_sizes, int n_in,
                              void* d_out, int out_size, void* d_ws, size_t ws_size,
                              hipStream_t stream) {
  const float* x     = (const float*)d_in[0];
  const float* eattr = (const float*)d_in[1];
  const int*   eidx  = (const int*)d_in[2];
  const int*   batch = (const int*)d_in[3];
  const float* wn    = (const float*)d_in[4];
  const float* bnb   = (const float*)d_in[5];
  const float* we    = (const float*)d_in[6];
  const float* be    = (const float*)d_in[7];
  const float* cw1   = (const float*)d_in[8];
  const float* cb1   = (const float*)d_in[9];
  const float* cg    = (const float*)d_in[10];
  const float* cbt   = (const float*)d_in[11];
  const float* cw2   = (const float*)d_in[12];
  const float* cb2   = (const float*)d_in[13];
  const float* wd    = (const float*)d_in[14];
  const float* bd    = (const float*)d_in[15];
  float* out = (float*)d_out;

  const int N = in_sizes[0] / 6;
  const int E = in_sizes[1] / 4;
  const int G = out_size;

  const int* src = eidx;
  const int* dst = eidx + E;

  char* ws = (char*)d_ws;
  size_t off = 0;
  auto alloc = [&](size_t bytes) -> char* {
    char* p = ws + off;
    off = (off + bytes + 255) & ~(size_t)255;
    return p;
  };
  float* h      = (float*)alloc((size_t)N * HH * 4);
  float* hres   = (float*)alloc((size_t)N * HH * 4);
  float* h1     = (float*)alloc((size_t)N * H2 * 4);
  int*   rowptr = (int*)alloc((size_t)(N + 1) * 4);
  int*   counts = (int*)alloc((size_t)N * 4);
  int*   fill   = (int*)alloc((size_t)N * 4);
  int*   ssrc   = (int*)alloc((size_t)E * 4);
  int*   seid   = (int*)alloc((size_t)E * 4);
  float* stats  = (float*)alloc(512 * 4);
  float* bnsc   = (float*)alloc(256 * 4);
  float* bnsh   = (float*)alloc(256 * 4);
  float* pool   = (float*)alloc((size_t)G * HH * 4);
  float* cntf   = (float*)alloc((size_t)G * 4);
  short* w1f    = (short*)alloc((size_t)3 * HH * H2 * 2);
  short* w2f    = (short*)alloc((size_t)3 * H2 * HH * 2);

  (void)ws_size; (void)n_in;

  hipMemsetAsync(counts, 0, (size_t)N * 4, stream);
  hipMemsetAsync(fill, 0, (size_t)N * 4, stream);
  hipMemsetAsync(pool, 0, (size_t)G * HH * 4, stream);
  hipMemsetAsync(cntf, 0, (size_t)G * 4, stream);

  // weight pre-convert to fragment-major bf16 (all 3 layers)
  k_wconv<<<dim3(128, 3), 256, 0, stream>>>(cw1, w1f, 8, HH);   // [128][256]
  k_wconv<<<dim3(128, 3), 256, 0, stream>>>(cw2, w2f, 7, H2);   // [256][128]

  k_encode<<<(N + 1) / 2, 256, 0, stream>>>(x, wn, bnb, h, N);
  k_hist<<<(E + 255) / 256, 256, 0, stream>>>(dst, counts, E);
  k_scan<<<1, 1024, 0, stream>>>(counts, rowptr, N);
  k_fill<<<(E + 255) / 256, 256, 0, stream>>>(src, dst, rowptr, fill, ssrc, seid, E);

  int mtiles = (N + 127) / 128;
  for (int layer = 0; layer < 3; ++layer) {
    const short* w1 = w1f + (size_t)layer * HH * H2;
    const float* b1 = cb1 + (size_t)layer * H2;
    const float* g_ = cg + (size_t)layer * H2;
    const float* bt = cbt + (size_t)layer * H2;
    const short* w2 = w2f + (size_t)layer * H2 * HH;
    const float* b2 = cb2 + (size_t)layer * HH;

    k_conv<<<N, 128, 0, stream>>>(h, eattr, we, be, rowptr, ssrc, seid, hres, N);
    hipMemsetAsync(stats, 0, 512 * 4, stream);
    k_mm1f<<<dim3(mtiles, 2), 256, 0, stream>>>(hres, w1, b1, h1, stats, stats + 256, N);
    k_bnfin<<<1, 256, 0, stream>>>(stats, stats + 256, g_, bt, bnsc, bnsh, 1.f / (float)N);
    k_mm2f<<<dim3(mtiles, 1), 256, 0, stream>>>(h1, w2, b2, bnsc, bnsh, h, N);
  }

  k_cnt<<<(N + 255) / 256, 256, 0, stream>>>(batch, cntf, N);
  k_pool<<<(N + 63) / 64, 128, 0, stream>>>(h, batch, pool, N);
  k_final<<<G, 64, 0, stream>>>(pool, cntf, wd, bd, out);
}

// Round 4
// 704.824 us; speedup vs baseline: 1.6819x; 1.0817x over previous
//
#include <hip/hip_runtime.h>
#include <hip/hip_fp16.h>

// ---------------------------------------------------------------------------
// GENConv GNN forward. Round 3: keep fp16 node features + bf16 intermediates
// + CSR-permuted edge_attr from round 2's plan, but revert k_conv to the
// proven block-per-node structure (suspected fault was the prefetch variant).
// ---------------------------------------------------------------------------

#define HH 128   // hidden
#define H2 256   // 2*hidden

typedef __attribute__((ext_vector_type(8))) short short8v;
typedef __attribute__((ext_vector_type(4))) float f32x4;

__device__ __forceinline__ short f2bf(float f) {
  union { float f; unsigned u; } v; v.f = f;
  unsigned r = v.u + 0x7fff + ((v.u >> 16) & 1);  // round-to-nearest-even
  return (short)(r >> 16);
}
__device__ __forceinline__ float bf2f(ushort s) {
  union { unsigned u; float f; } v; v.u = ((unsigned)s) << 16;
  return v.f;
}

// ---- node encoder: h16 = fp16(x @ wn + bn)   (x: [N,6], wn: [6,128]) ----
__global__ void k_encode(const float* __restrict__ x, const float* __restrict__ wn,
                         const float* __restrict__ bnb, __half* __restrict__ h16, int n) {
  int c = threadIdx.x & 127;
  int node = blockIdx.x * 2 + (threadIdx.x >> 7);
  if (node >= n) return;
  const float* xr = x + (size_t)node * 6;
  float acc = bnb[c];
#pragma unroll
  for (int k = 0; k < 6; ++k) acc = fmaf(xr[k], wn[k * HH + c], acc);
  h16[(size_t)node * HH + c] = __float2half(acc);
}

// ---- CSR build ----
__global__ void k_hist(const int* __restrict__ dst, int* __restrict__ counts, int E) {
  int e = blockIdx.x * 256 + threadIdx.x;
  if (e < E) atomicAdd(&counts[dst[e]], 1);
}

__global__ void k_scan(const int* __restrict__ counts, int* __restrict__ rowptr, int n) {
  __shared__ int wsum[16];
  __shared__ int carry;
  int t = threadIdx.x;
  int lane = t & 63, w = t >> 6;
  if (t == 0) carry = 0;
  __syncthreads();
  for (int base = 0; base < n; base += 1024) {
    int v = (base + t < n) ? counts[base + t] : 0;
    int x = v;
#pragma unroll
    for (int d = 1; d < 64; d <<= 1) {
      int y = __shfl_up(x, d);
      if (lane >= d) x += y;
    }
    if (lane == 63) wsum[w] = x;
    __syncthreads();
    if (w == 0 && lane < 16) {
      int s = wsum[lane];
#pragma unroll
      for (int d = 1; d < 16; d <<= 1) {
        int y = __shfl_up(s, d);
        if (lane >= d) s += y;
      }
      wsum[lane] = s;
    }
    __syncthreads();
    int waveoff = (w == 0) ? 0 : wsum[w - 1];
    int c0 = carry;
    if (base + t < n) rowptr[base + t] = c0 + waveoff + x - v;
    __syncthreads();
    if (t == 0) carry = c0 + wsum[15];
    __syncthreads();
  }
  if (t == 0) rowptr[n] = carry;
}

// scatter edges into CSR order; also permute edge_attr for sequential reads
__global__ void k_fill(const int* __restrict__ src, const int* __restrict__ dst,
                       const float4* __restrict__ eattr,
                       const int* __restrict__ rowptr, int* __restrict__ fill,
                       int* __restrict__ ssrc, float4* __restrict__ eattrs, int E) {
  int e = blockIdx.x * 256 + threadIdx.x;
  if (e >= E) return;
  int d = dst[e];
  int pos = rowptr[d] + atomicAdd(&fill[d], 1);
  ssrc[pos] = src[e];
  eattrs[pos] = eattr[e];
}

// ---- GENConv message + softmax aggregation (online softmax over CSR) ----
// one block (128 threads) per dst node; thread = channel  [round-2 structure]
__global__ __launch_bounds__(128) void k_conv(
    const __half* __restrict__ h16, const float4* __restrict__ eattrs,
    const float* __restrict__ we, const float* __restrict__ be,
    const int* __restrict__ rowptr, const int* __restrict__ ssrc,
    ushort* __restrict__ hresb, int n) {
  int d = blockIdx.x;
  int c = threadIdx.x;
  float w0 = we[c], w1 = we[HH + c], w2 = we[2 * HH + c], w3 = we[3 * HH + c];
  float bec = be[c];
  int p0 = rowptr[d], p1 = rowptr[d + 1];
  float M = -1e30f, S = 0.f, W = 0.f;
  for (int p = p0; p < p1; ++p) {
    int s = ssrc[p];
    float4 a = eattrs[p];
    float eac = fmaf(a.x, w0, fmaf(a.y, w1, fmaf(a.z, w2, fmaf(a.w, w3, bec))));
    float hv = __half2float(h16[(size_t)s * HH + c]);
    float m = fmaxf(hv + eac, 0.f) + 1e-7f;
    float newM = fmaxf(M, m);
    float sc = __expf(M - newM);
    float em = __expf(m - newM);
    S = fmaf(S, sc, em);
    W = fmaf(W, sc, m * em);
    M = newM;
  }
  float hd = __half2float(h16[(size_t)d * HH + c]);
  float r = W / (S + 1e-16f) + hd;
  hresb[(size_t)d * HH + c] = (ushort)f2bf(r);
}

// ---- weight pre-convert: fp32 [K][Ncols] -> bf16 fragment-major ----
__global__ void k_wconv(const float* __restrict__ W, short* __restrict__ out,
                        int logn, int K) {
  int layer = blockIdx.y;
  int total = K << logn;
  int e = blockIdx.x * 256 + threadIdx.x;
  if (e >= total) return;
  const float* Wl = W + (size_t)layer * total;
  short* ol = out + (size_t)layer * total;
  int k = e >> logn, col = e & ((1 << logn) - 1);
  int ty = col >> 7, colL = col & 127;
  int wc = colL >> 6, n = (colL >> 4) & 3, l15 = colL & 15;
  int kc = k >> 7, kl = k & 127;
  int ksl = kl >> 5, lhi = (kl >> 3) & 3, j = kl & 7;
  int KC = K >> 7;
  size_t idx = (size_t)(ty * KC + kc) * 16384 +
               ((((wc * 4 + n) * 4 + ksl) * 64 + lhi * 16 + l15) * 8 + j);
  ol[idx] = f2bf(Wl[e]);
}

// ---- mm1 (MFMA): h1b = bf16(hresb @ w1 + b1), BN sum/sumsq ----
// A: [M,128] bf16 row-major, Bf: fragment-major bf16, C: [M,256] bf16
__global__ __launch_bounds__(256) void k_mm1f(
    const ushort* __restrict__ Ab, const short* __restrict__ Bf,
    const float* __restrict__ bias, ushort* __restrict__ Cb,
    float* __restrict__ bnsum, float* __restrict__ bnsq, int M) {
  __shared__ short As[16384];
  __shared__ short Bs[16384];
  int t = threadIdx.x;
  int row0 = blockIdx.x * 128;
  int ty = blockIdx.y;
  // stage B (pure 16B copy, already fragment-major)
  {
    const short8v* srcB = (const short8v*)(Bf + (size_t)ty * 16384);
    short8v* dstB = (short8v*)Bs;
#pragma unroll
    for (int i = 0; i < 8; ++i) dstB[i * 256 + t] = srcB[i * 256 + t];
  }
  // stage A: bf16 row-major -> fragment-major (pure 16B moves)
  {
    int l15 = t & 15, k8 = t >> 4;
    int ksl = k8 >> 2, lhi = k8 & 3;
#pragma unroll
    for (int i = 0; i < 8; ++i) {
      int grow = row0 + i * 16 + l15;
      short8v v = {0, 0, 0, 0, 0, 0, 0, 0};
      if (grow < M) v = *(const short8v*)(Ab + (size_t)grow * HH + k8 * 8);
      *(short8v*)&As[((i * 4 + ksl) * 64 + lhi * 16 + l15) * 8] = v;
    }
  }
  __syncthreads();
  int lane = t & 63, w = t >> 6;
  int wr = w >> 1, wc = w & 1;
  f32x4 acc[4][4];
#pragma unroll
  for (int m = 0; m < 4; ++m)
#pragma unroll
    for (int n = 0; n < 4; ++n) acc[m][n] = (f32x4){0.f, 0.f, 0.f, 0.f};
#pragma unroll
  for (int ksl = 0; ksl < 4; ++ksl) {
    short8v a[4], b[4];
#pragma unroll
    for (int m = 0; m < 4; ++m)
      a[m] = *(const short8v*)&As[(((wr * 4 + m) * 4 + ksl) * 64 + lane) * 8];
#pragma unroll
    for (int n = 0; n < 4; ++n)
      b[n] = *(const short8v*)&Bs[(((wc * 4 + n) * 4 + ksl) * 64 + lane) * 8];
#pragma unroll
    for (int m = 0; m < 4; ++m)
#pragma unroll
      for (int n = 0; n < 4; ++n)
        acc[m][n] = __builtin_amdgcn_mfma_f32_16x16x32_bf16(a[m], b[n], acc[m][n], 0, 0, 0);
  }
  __syncthreads();
  // reuse As as BN reduction buffer: [0..127]=sum, [128..255]=sumsq
  float* red = (float*)As;
  red[t] = 0.f;
  __syncthreads();
  int l15c = lane & 15, rq = lane >> 4;
#pragma unroll
  for (int n = 0; n < 4; ++n) {
    int colL = wc * 64 + n * 16 + l15c;
    float bb = bias[ty * 128 + colL];
    float cs = 0.f, cq = 0.f;
#pragma unroll
    for (int m = 0; m < 4; ++m) {
      int rbase = row0 + wr * 64 + m * 16 + rq * 4;
#pragma unroll
      for (int r = 0; r < 4; ++r) {
        int row = rbase + r;
        if (row < M) {
          float o = acc[m][n][r] + bb;
          Cb[(size_t)row * H2 + ty * 128 + colL] = (ushort)f2bf(o);
          cs += o; cq += o * o;
        }
      }
    }
    atomicAdd(&red[colL], cs);
    atomicAdd(&red[128 + colL], cq);
  }
  __syncthreads();
  if (t < 128) {
    atomicAdd(&bnsum[ty * 128 + t], red[t]);
    atomicAdd(&bnsq[ty * 128 + t], red[128 + t]);
  }
}

// ---- fold BN stats into per-channel scale/shift ----
__global__ void k_bnfin(const float* __restrict__ bnsum, const float* __restrict__ bnsq,
                        const float* __restrict__ g, const float* __restrict__ bt,
                        float* __restrict__ scale, float* __restrict__ shift, float invN) {
  int c = threadIdx.x;
  float mu = bnsum[c] * invN;
  float var = bnsq[c] * invN - mu * mu;
  float rs = rsqrtf(var + 1e-5f);
  float sc = rs * g[c];
  scale[c] = sc;
  shift[c] = bt[c] - mu * sc;
}

// ---- mm2 (MFMA): h16 = fp16( relu( relu(h1b*scale+shift) @ w2 + b2 ) ) ----
__global__ __launch_bounds__(256) void k_mm2f(
    const ushort* __restrict__ Ab, const short* __restrict__ Bf,
    const float* __restrict__ bias, const float* __restrict__ scale,
    const float* __restrict__ shift, __half* __restrict__ h16, int M) {
  __shared__ short As[16384];
  __shared__ short Bs[16384];
  int t = threadIdx.x;
  int row0 = blockIdx.x * 128;
  int lane = t & 63, w = t >> 6;
  int wr = w >> 1, wc = w & 1;
  int l15 = t & 15, k8 = t >> 4;
  int ksl0 = k8 >> 2, lhi = k8 & 3;
  f32x4 acc[4][4];
#pragma unroll
  for (int m = 0; m < 4; ++m)
#pragma unroll
    for (int n = 0; n < 4; ++n) acc[m][n] = (f32x4){0.f, 0.f, 0.f, 0.f};
#pragma unroll 1
  for (int kc = 0; kc < 2; ++kc) {
    if (kc) __syncthreads();
    // stage B
    {
      const short8v* srcB = (const short8v*)(Bf + (size_t)kc * 16384);
      short8v* dstB = (short8v*)Bs;
#pragma unroll
      for (int i = 0; i < 8; ++i) dstB[i * 256 + t] = srcB[i * 256 + t];
    }
    // stage A: load bf16, unpack, BN scale/shift + relu, repack bf16
    {
      float scf[8], shf[8];
#pragma unroll
      for (int j = 0; j < 8; ++j) {
        scf[j] = scale[kc * 128 + k8 * 8 + j];
        shf[j] = shift[kc * 128 + k8 * 8 + j];
      }
#pragma unroll
      for (int i = 0; i < 8; ++i) {
        int grow = row0 + i * 16 + l15;
        short8v v = {0, 0, 0, 0, 0, 0, 0, 0};
        if (grow < M) {
          short8v raw = *(const short8v*)(Ab + (size_t)grow * H2 + kc * 128 + k8 * 8);
#pragma unroll
          for (int j = 0; j < 8; ++j) {
            float f = bf2f((ushort)raw[j]);
            f = fmaxf(fmaf(f, scf[j], shf[j]), 0.f);
            v[j] = f2bf(f);
          }
        }
        *(short8v*)&As[((i * 4 + ksl0) * 64 + lhi * 16 + l15) * 8] = v;
      }
    }
    __syncthreads();
#pragma unroll
    for (int ksl = 0; ksl < 4; ++ksl) {
      short8v a[4], b[4];
#pragma unroll
      for (int m = 0; m < 4; ++m)
        a[m] = *(const short8v*)&As[(((wr * 4 + m) * 4 + ksl) * 64 + lane) * 8];
#pragma unroll
      for (int n = 0; n < 4; ++n)
        b[n] = *(const short8v*)&Bs[(((wc * 4 + n) * 4 + ksl) * 64 + lane) * 8];
#pragma unroll
      for (int m = 0; m < 4; ++m)
#pragma unroll
        for (int n = 0; n < 4; ++n)
          acc[m][n] = __builtin_amdgcn_mfma_f32_16x16x32_bf16(a[m], b[n], acc[m][n], 0, 0, 0);
    }
  }
  int l15c = lane & 15, rq = lane >> 4;
#pragma unroll
  for (int n = 0; n < 4; ++n) {
    int colL = wc * 64 + n * 16 + l15c;
    float bb = bias[colL];
#pragma unroll
    for (int m = 0; m < 4; ++m) {
      int rbase = row0 + wr * 64 + m * 16 + rq * 4;
#pragma unroll
      for (int r = 0; r < 4; ++r) {
        int row = rbase + r;
        if (row < M)
          h16[(size_t)row * HH + colL] = __float2half(fmaxf(acc[m][n][r] + bb, 0.f));
      }
    }
  }
}

// ---- graph node counts ----
__global__ void k_cnt(const int* __restrict__ batch, float* __restrict__ cntf, int n) {
  int i = blockIdx.x * 256 + threadIdx.x;
  if (i < n) atomicAdd(&cntf[batch[i]], 1.f);
}

// ---- mean-pool partial sums (batch sorted -> run-length accumulate) ----
__global__ __launch_bounds__(128) void k_pool(const __half* __restrict__ h16,
                                              const int* __restrict__ batch,
                                              float* __restrict__ pool, int n) {
  int c = threadIdx.x;
  int n0 = blockIdx.x * 64;
  int nend = min(n0 + 64, n);
  float acc = 0.f;
  int gprev = batch[n0];
  for (int i = n0; i < nend; ++i) {
    int g = batch[i];
    if (g != gprev) {
      atomicAdd(&pool[(size_t)gprev * HH + c], acc);
      acc = 0.f;
      gprev = g;
    }
    acc += __half2float(h16[(size_t)i * HH + c]);
  }
  atomicAdd(&pool[(size_t)gprev * HH + c], acc);
}

// ---- final: sigmoid(mean_pool @ wd + bd) ----
__global__ __launch_bounds__(64) void k_final(const float* __restrict__ pool,
                                              const float* __restrict__ cntf,
                                              const float* __restrict__ wd,
                                              const float* __restrict__ bd,
                                              float* __restrict__ out) {
  int g = blockIdx.x;
  int t = threadIdx.x;
  float inv = 1.f / fmaxf(cntf[g], 1.f);
  float v = pool[(size_t)g * HH + t] * inv * wd[t] +
            pool[(size_t)g * HH + 64 + t] * inv * wd[64 + t];
#pragma unroll
  for (int d = 32; d; d >>= 1) v += __shfl_down(v, d);
  if (t == 0) out[g] = 1.f / (1.f + __expf(-(v + bd[0])));
}

// ---------------------------------------------------------------------------
extern "C" void kernel_launch(void* const* d_in, const int* in_sizes, int n_in,
                              void* d_out, int out_size, void* d_ws, size_t ws_size,
                              hipStream_t stream) {
  const float* x     = (const float*)d_in[0];
  const float* eattr = (const float*)d_in[1];
  const int*   eidx  = (const int*)d_in[2];
  const int*   batch = (const int*)d_in[3];
  const float* wn    = (const float*)d_in[4];
  const float* bnb   = (const float*)d_in[5];
  const float* we    = (const float*)d_in[6];
  const float* be    = (const float*)d_in[7];
  const float* cw1   = (const float*)d_in[8];
  const float* cb1   = (const float*)d_in[9];
  const float* cg    = (const float*)d_in[10];
  const float* cbt   = (const float*)d_in[11];
  const float* cw2   = (const float*)d_in[12];
  const float* cb2   = (const float*)d_in[13];
  const float* wd    = (const float*)d_in[14];
  const float* bd    = (const float*)d_in[15];
  float* out = (float*)d_out;

  const int N = in_sizes[0] / 6;
  const int E = in_sizes[1] / 4;
  const int G = out_size;

  const int* src = eidx;
  const int* dst = eidx + E;

  char* ws = (char*)d_ws;
  size_t off = 0;
  auto alloc = [&](size_t bytes) -> char* {
    char* p = ws + off;
    off = (off + bytes + 255) & ~(size_t)255;
    return p;
  };
  __half* h16    = (__half*)alloc((size_t)N * HH * 2);
  ushort* hresb  = (ushort*)alloc((size_t)N * HH * 2);
  ushort* h1b    = (ushort*)alloc((size_t)N * H2 * 2);
  int*    rowptr = (int*)alloc((size_t)(N + 1) * 4);
  int*    counts = (int*)alloc((size_t)N * 4);
  int*    fill   = (int*)alloc((size_t)N * 4);
  int*    ssrc   = (int*)alloc((size_t)E * 4);
  float4* eattrs = (float4*)alloc((size_t)E * 16);
  float*  stats  = (float*)alloc(512 * 4);
  float*  bnsc   = (float*)alloc(256 * 4);
  float*  bnsh   = (float*)alloc(256 * 4);
  float*  pool   = (float*)alloc((size_t)G * HH * 4);
  float*  cntf   = (float*)alloc((size_t)G * 4);
  short*  w1f    = (short*)alloc((size_t)3 * HH * H2 * 2);
  short*  w2f    = (short*)alloc((size_t)3 * H2 * HH * 2);

  (void)ws_size; (void)n_in;

  hipMemsetAsync(counts, 0, (size_t)N * 4, stream);
  hipMemsetAsync(fill, 0, (size_t)N * 4, stream);
  hipMemsetAsync(pool, 0, (size_t)G * HH * 4, stream);
  hipMemsetAsync(cntf, 0, (size_t)G * 4, stream);

  // weight pre-convert to fragment-major bf16 (all 3 layers)
  k_wconv<<<dim3(128, 3), 256, 0, stream>>>(cw1, w1f, 8, HH);   // [128][256]
  k_wconv<<<dim3(128, 3), 256, 0, stream>>>(cw2, w2f, 7, H2);   // [256][128]

  k_encode<<<(N + 1) / 2, 256, 0, stream>>>(x, wn, bnb, h16, N);
  k_hist<<<(E + 255) / 256, 256, 0, stream>>>(dst, counts, E);
  k_scan<<<1, 1024, 0, stream>>>(counts, rowptr, N);
  k_fill<<<(E + 255) / 256, 256, 0, stream>>>(src, dst, (const float4*)eattr,
                                              rowptr, fill, ssrc, eattrs, E);

  int mtiles = (N + 127) / 128;
  for (int layer = 0; layer < 3; ++layer) {
    const short* w1 = w1f + (size_t)layer * HH * H2;
    const float* b1 = cb1 + (size_t)layer * H2;
    const float* g_ = cg + (size_t)layer * H2;
    const float* bt = cbt + (size_t)layer * H2;
    const short* w2 = w2f + (size_t)layer * H2 * HH;
    const float* b2 = cb2 + (size_t)layer * HH;

    k_conv<<<N, 128, 0, stream>>>(h16, eattrs, we, be, rowptr, ssrc, hresb, N);
    hipMemsetAsync(stats, 0, 512 * 4, stream);
    k_mm1f<<<dim3(mtiles, 2), 256, 0, stream>>>(hresb, w1, b1, h1b, stats, stats + 256, N);
    k_bnfin<<<1, 256, 0, stream>>>(stats, stats + 256, g_, bt, bnsc, bnsh, 1.f / (float)N);
    k_mm2f<<<dim3(mtiles, 1), 256, 0, stream>>>(h1b, w2, b2, bnsc, bnsh, h16, N);
  }

  k_cnt<<<(N + 255) / 256, 256, 0, stream>>>(batch, cntf, N);
  k_pool<<<(N + 63) / 64, 128, 0, stream>>>(h16, batch, pool, N);
  k_final<<<G, 64, 0, stream>>>(pool, cntf, wd, bd, out);
}

// Round 5
// 613.290 us; speedup vs baseline: 1.9329x; 1.1493x over previous
//
#include <hip/hip_runtime.h>
#include <hip/hip_fp16.h>

// ---------------------------------------------------------------------------
// GENConv GNN forward. Round 4: k_conv drops online-max tracking (exp range
// is BN-bounded, softmax ratio identical) + 2-way unrolled dual-accumulator
// edge loop (two independent gather chains in flight). Vectorized k_scan.
// ---------------------------------------------------------------------------

#define HH 128   // hidden
#define H2 256   // 2*hidden

typedef __attribute__((ext_vector_type(8))) short short8v;
typedef __attribute__((ext_vector_type(4))) float f32x4;

__device__ __forceinline__ short f2bf(float f) {
  union { float f; unsigned u; } v; v.f = f;
  unsigned r = v.u + 0x7fff + ((v.u >> 16) & 1);  // round-to-nearest-even
  return (short)(r >> 16);
}
__device__ __forceinline__ float bf2f(ushort s) {
  union { unsigned u; float f; } v; v.u = ((unsigned)s) << 16;
  return v.f;
}

// ---- node encoder: h16 = fp16(x @ wn + bn)   (x: [N,6], wn: [6,128]) ----
__global__ void k_encode(const float* __restrict__ x, const float* __restrict__ wn,
                         const float* __restrict__ bnb, __half* __restrict__ h16, int n) {
  int c = threadIdx.x & 127;
  int node = blockIdx.x * 2 + (threadIdx.x >> 7);
  if (node >= n) return;
  const float* xr = x + (size_t)node * 6;
  float acc = bnb[c];
#pragma unroll
  for (int k = 0; k < 6; ++k) acc = fmaf(xr[k], wn[k * HH + c], acc);
  h16[(size_t)node * HH + c] = __float2half(acc);
}

// ---- CSR build ----
__global__ void k_hist(const int* __restrict__ dst, int* __restrict__ counts, int E) {
  int e = blockIdx.x * 256 + threadIdx.x;
  if (e < E) atomicAdd(&counts[dst[e]], 1);
}

// single-block exclusive scan, 4 elements/thread per pass (int4)
__global__ void k_scan(const int* __restrict__ counts, int* __restrict__ rowptr, int n) {
  __shared__ int wsum[16];
  __shared__ int carry;
  int t = threadIdx.x;
  int lane = t & 63, w = t >> 6;
  if (t == 0) carry = 0;
  __syncthreads();
  for (int base = 0; base < n; base += 4096) {
    int idx = base + t * 4;
    int4 v = make_int4(0, 0, 0, 0);
    if (idx + 3 < n) {
      v = *(const int4*)(counts + idx);
    } else {
      if (idx < n)     v.x = counts[idx];
      if (idx + 1 < n) v.y = counts[idx + 1];
      if (idx + 2 < n) v.z = counts[idx + 2];
    }
    int tsum = v.x + v.y + v.z + v.w;
    int x = tsum;
#pragma unroll
    for (int d = 1; d < 64; d <<= 1) {
      int y = __shfl_up(x, d);
      if (lane >= d) x += y;
    }
    if (lane == 63) wsum[w] = x;
    __syncthreads();
    if (w == 0 && lane < 16) {
      int s = wsum[lane];
#pragma unroll
      for (int d = 1; d < 16; d <<= 1) {
        int y = __shfl_up(s, d);
        if (lane >= d) s += y;
      }
      wsum[lane] = s;
    }
    __syncthreads();
    int waveoff = (w == 0) ? 0 : wsum[w - 1];
    int c0 = carry;
    int excl = c0 + waveoff + x - tsum;
    int4 o;
    o.x = excl;
    o.y = excl + v.x;
    o.z = o.y + v.y;
    o.w = o.z + v.z;
    if (idx + 3 < n) {
      *(int4*)(rowptr + idx) = o;
    } else {
      if (idx < n)     rowptr[idx] = o.x;
      if (idx + 1 < n) rowptr[idx + 1] = o.y;
      if (idx + 2 < n) rowptr[idx + 2] = o.z;
    }
    __syncthreads();
    if (t == 0) carry = c0 + wsum[15];
    __syncthreads();
  }
  if (t == 0) rowptr[n] = carry;
}

// scatter edges into CSR order; also permute edge_attr for sequential reads
__global__ void k_fill(const int* __restrict__ src, const int* __restrict__ dst,
                       const float4* __restrict__ eattr,
                       const int* __restrict__ rowptr, int* __restrict__ fill,
                       int* __restrict__ ssrc, float4* __restrict__ eattrs, int E) {
  int e = blockIdx.x * 256 + threadIdx.x;
  if (e >= E) return;
  int d = dst[e];
  int pos = rowptr[d] + atomicAdd(&fill[d], 1);
  ssrc[pos] = src[e];
  eattrs[pos] = eattr[e];
}

// ---- GENConv message + softmax aggregation over CSR ----
// one block (128 threads) per dst node; thread = channel.
// No max-tracking (exp args BN-bounded); 2-way unroll, dual accumulators.
__global__ __launch_bounds__(128) void k_conv(
    const __half* __restrict__ h16, const float4* __restrict__ eattrs,
    const float* __restrict__ we, const float* __restrict__ be,
    const int* __restrict__ rowptr, const int* __restrict__ ssrc,
    ushort* __restrict__ hresb, int n) {
  int d = blockIdx.x;
  int c = threadIdx.x;
  float w0 = we[c], w1 = we[HH + c], w2 = we[2 * HH + c], w3 = we[3 * HH + c];
  float bec = be[c];
  int p0 = rowptr[d], p1 = rowptr[d + 1];
  float Sa = 0.f, Wa = 0.f, Sb = 0.f, Wb = 0.f;
  int p = p0;
  for (; p + 2 <= p1; p += 2) {
    int sA = ssrc[p];
    int sB = ssrc[p + 1];
    float4 aA = eattrs[p];
    float4 aB = eattrs[p + 1];
    float hA = __half2float(h16[(size_t)sA * HH + c]);
    float hB = __half2float(h16[(size_t)sB * HH + c]);
    float eacA = fmaf(aA.x, w0, fmaf(aA.y, w1, fmaf(aA.z, w2, fmaf(aA.w, w3, bec))));
    float eacB = fmaf(aB.x, w0, fmaf(aB.y, w1, fmaf(aB.z, w2, fmaf(aB.w, w3, bec))));
    float mA = fmaxf(hA + eacA, 0.f) + 1e-7f;
    float mB = fmaxf(hB + eacB, 0.f) + 1e-7f;
    float eA = __expf(mA);
    float eB = __expf(mB);
    Sa += eA; Wa = fmaf(mA, eA, Wa);
    Sb += eB; Wb = fmaf(mB, eB, Wb);
  }
  if (p < p1) {
    int s = ssrc[p];
    float4 a = eattrs[p];
    float hv = __half2float(h16[(size_t)s * HH + c]);
    float eac = fmaf(a.x, w0, fmaf(a.y, w1, fmaf(a.z, w2, fmaf(a.w, w3, bec))));
    float m = fmaxf(hv + eac, 0.f) + 1e-7f;
    float e = __expf(m);
    Sa += e; Wa = fmaf(m, e, Wa);
  }
  float S = Sa + Sb, W = Wa + Wb;
  float hd = __half2float(h16[(size_t)d * HH + c]);
  float r = W / (S + 1e-16f) + hd;
  hresb[(size_t)d * HH + c] = (ushort)f2bf(r);
}

// ---- weight pre-convert: fp32 [K][Ncols] -> bf16 fragment-major ----
__global__ void k_wconv(const float* __restrict__ W, short* __restrict__ out,
                        int logn, int K) {
  int layer = blockIdx.y;
  int total = K << logn;
  int e = blockIdx.x * 256 + threadIdx.x;
  if (e >= total) return;
  const float* Wl = W + (size_t)layer * total;
  short* ol = out + (size_t)layer * total;
  int k = e >> logn, col = e & ((1 << logn) - 1);
  int ty = col >> 7, colL = col & 127;
  int wc = colL >> 6, n = (colL >> 4) & 3, l15 = colL & 15;
  int kc = k >> 7, kl = k & 127;
  int ksl = kl >> 5, lhi = (kl >> 3) & 3, j = kl & 7;
  int KC = K >> 7;
  size_t idx = (size_t)(ty * KC + kc) * 16384 +
               ((((wc * 4 + n) * 4 + ksl) * 64 + lhi * 16 + l15) * 8 + j);
  ol[idx] = f2bf(Wl[e]);
}

// ---- mm1 (MFMA): h1b = bf16(hresb @ w1 + b1), BN sum/sumsq ----
__global__ __launch_bounds__(256) void k_mm1f(
    const ushort* __restrict__ Ab, const short* __restrict__ Bf,
    const float* __restrict__ bias, ushort* __restrict__ Cb,
    float* __restrict__ bnsum, float* __restrict__ bnsq, int M) {
  __shared__ short As[16384];
  __shared__ short Bs[16384];
  int t = threadIdx.x;
  int row0 = blockIdx.x * 128;
  int ty = blockIdx.y;
  {
    const short8v* srcB = (const short8v*)(Bf + (size_t)ty * 16384);
    short8v* dstB = (short8v*)Bs;
#pragma unroll
    for (int i = 0; i < 8; ++i) dstB[i * 256 + t] = srcB[i * 256 + t];
  }
  {
    int l15 = t & 15, k8 = t >> 4;
    int ksl = k8 >> 2, lhi = k8 & 3;
#pragma unroll
    for (int i = 0; i < 8; ++i) {
      int grow = row0 + i * 16 + l15;
      short8v v = {0, 0, 0, 0, 0, 0, 0, 0};
      if (grow < M) v = *(const short8v*)(Ab + (size_t)grow * HH + k8 * 8);
      *(short8v*)&As[((i * 4 + ksl) * 64 + lhi * 16 + l15) * 8] = v;
    }
  }
  __syncthreads();
  int lane = t & 63, w = t >> 6;
  int wr = w >> 1, wc = w & 1;
  f32x4 acc[4][4];
#pragma unroll
  for (int m = 0; m < 4; ++m)
#pragma unroll
    for (int n = 0; n < 4; ++n) acc[m][n] = (f32x4){0.f, 0.f, 0.f, 0.f};
#pragma unroll
  for (int ksl = 0; ksl < 4; ++ksl) {
    short8v a[4], b[4];
#pragma unroll
    for (int m = 0; m < 4; ++m)
      a[m] = *(const short8v*)&As[(((wr * 4 + m) * 4 + ksl) * 64 + lane) * 8];
#pragma unroll
    for (int n = 0; n < 4; ++n)
      b[n] = *(const short8v*)&Bs[(((wc * 4 + n) * 4 + ksl) * 64 + lane) * 8];
#pragma unroll
    for (int m = 0; m < 4; ++m)
#pragma unroll
      for (int n = 0; n < 4; ++n)
        acc[m][n] = __builtin_amdgcn_mfma_f32_16x16x32_bf16(a[m], b[n], acc[m][n], 0, 0, 0);
  }
  __syncthreads();
  float* red = (float*)As;
  red[t] = 0.f;
  __syncthreads();
  int l15c = lane & 15, rq = lane >> 4;
#pragma unroll
  for (int n = 0; n < 4; ++n) {
    int colL = wc * 64 + n * 16 + l15c;
    float bb = bias[ty * 128 + colL];
    float cs = 0.f, cq = 0.f;
#pragma unroll
    for (int m = 0; m < 4; ++m) {
      int rbase = row0 + wr * 64 + m * 16 + rq * 4;
#pragma unroll
      for (int r = 0; r < 4; ++r) {
        int row = rbase + r;
        if (row < M) {
          float o = acc[m][n][r] + bb;
          Cb[(size_t)row * H2 + ty * 128 + colL] = (ushort)f2bf(o);
          cs += o; cq += o * o;
        }
      }
    }
    atomicAdd(&red[colL], cs);
    atomicAdd(&red[128 + colL], cq);
  }
  __syncthreads();
  if (t < 128) {
    atomicAdd(&bnsum[ty * 128 + t], red[t]);
    atomicAdd(&bnsq[ty * 128 + t], red[128 + t]);
  }
}

// ---- fold BN stats into per-channel scale/shift ----
__global__ void k_bnfin(const float* __restrict__ bnsum, const float* __restrict__ bnsq,
                        const float* __restrict__ g, const float* __restrict__ bt,
                        float* __restrict__ scale, float* __restrict__ shift, float invN) {
  int c = threadIdx.x;
  float mu = bnsum[c] * invN;
  float var = bnsq[c] * invN - mu * mu;
  float rs = rsqrtf(var + 1e-5f);
  float sc = rs * g[c];
  scale[c] = sc;
  shift[c] = bt[c] - mu * sc;
}

// ---- mm2 (MFMA): h16 = fp16( relu( relu(h1b*scale+shift) @ w2 + b2 ) ) ----
__global__ __launch_bounds__(256) void k_mm2f(
    const ushort* __restrict__ Ab, const short* __restrict__ Bf,
    const float* __restrict__ bias, const float* __restrict__ scale,
    const float* __restrict__ shift, __half* __restrict__ h16, int M) {
  __shared__ short As[16384];
  __shared__ short Bs[16384];
  int t = threadIdx.x;
  int row0 = blockIdx.x * 128;
  int lane = t & 63, w = t >> 6;
  int wr = w >> 1, wc = w & 1;
  int l15 = t & 15, k8 = t >> 4;
  int ksl0 = k8 >> 2, lhi = k8 & 3;
  f32x4 acc[4][4];
#pragma unroll
  for (int m = 0; m < 4; ++m)
#pragma unroll
    for (int n = 0; n < 4; ++n) acc[m][n] = (f32x4){0.f, 0.f, 0.f, 0.f};
#pragma unroll 1
  for (int kc = 0; kc < 2; ++kc) {
    if (kc) __syncthreads();
    {
      const short8v* srcB = (const short8v*)(Bf + (size_t)kc * 16384);
      short8v* dstB = (short8v*)Bs;
#pragma unroll
      for (int i = 0; i < 8; ++i) dstB[i * 256 + t] = srcB[i * 256 + t];
    }
    {
      float scf[8], shf[8];
#pragma unroll
      for (int j = 0; j < 8; ++j) {
        scf[j] = scale[kc * 128 + k8 * 8 + j];
        shf[j] = shift[kc * 128 + k8 * 8 + j];
      }
#pragma unroll
      for (int i = 0; i < 8; ++i) {
        int grow = row0 + i * 16 + l15;
        short8v v = {0, 0, 0, 0, 0, 0, 0, 0};
        if (grow < M) {
          short8v raw = *(const short8v*)(Ab + (size_t)grow * H2 + kc * 128 + k8 * 8);
#pragma unroll
          for (int j = 0; j < 8; ++j) {
            float f = bf2f((ushort)raw[j]);
            f = fmaxf(fmaf(f, scf[j], shf[j]), 0.f);
            v[j] = f2bf(f);
          }
        }
        *(short8v*)&As[((i * 4 + ksl0) * 64 + lhi * 16 + l15) * 8] = v;
      }
    }
    __syncthreads();
#pragma unroll
    for (int ksl = 0; ksl < 4; ++ksl) {
      short8v a[4], b[4];
#pragma unroll
      for (int m = 0; m < 4; ++m)
        a[m] = *(const short8v*)&As[(((wr * 4 + m) * 4 + ksl) * 64 + lane) * 8];
#pragma unroll
      for (int n = 0; n < 4; ++n)
        b[n] = *(const short8v*)&Bs[(((wc * 4 + n) * 4 + ksl) * 64 + lane) * 8];
#pragma unroll
      for (int m = 0; m < 4; ++m)
#pragma unroll
        for (int n = 0; n < 4; ++n)
          acc[m][n] = __builtin_amdgcn_mfma_f32_16x16x32_bf16(a[m], b[n], acc[m][n], 0, 0, 0);
    }
  }
  int l15c = lane & 15, rq = lane >> 4;
#pragma unroll
  for (int n = 0; n < 4; ++n) {
    int colL = wc * 64 + n * 16 + l15c;
    float bb = bias[colL];
#pragma unroll
    for (int m = 0; m < 4; ++m) {
      int rbase = row0 + wr * 64 + m * 16 + rq * 4;
#pragma unroll
      for (int r = 0; r < 4; ++r) {
        int row = rbase + r;
        if (row < M)
          h16[(size_t)row * HH + colL] = __float2half(fmaxf(acc[m][n][r] + bb, 0.f));
      }
    }
  }
}

// ---- graph node counts ----
__global__ void k_cnt(const int* __restrict__ batch, float* __restrict__ cntf, int n) {
  int i = blockIdx.x * 256 + threadIdx.x;
  if (i < n) atomicAdd(&cntf[batch[i]], 1.f);
}

// ---- mean-pool partial sums (batch sorted -> run-length accumulate) ----
__global__ __launch_bounds__(128) void k_pool(const __half* __restrict__ h16,
                                              const int* __restrict__ batch,
                                              float* __restrict__ pool, int n) {
  int c = threadIdx.x;
  int n0 = blockIdx.x * 64;
  int nend = min(n0 + 64, n);
  float acc = 0.f;
  int gprev = batch[n0];
  for (int i = n0; i < nend; ++i) {
    int g = batch[i];
    if (g != gprev) {
      atomicAdd(&pool[(size_t)gprev * HH + c], acc);
      acc = 0.f;
      gprev = g;
    }
    acc += __half2float(h16[(size_t)i * HH + c]);
  }
  atomicAdd(&pool[(size_t)gprev * HH + c], acc);
}

// ---- final: sigmoid(mean_pool @ wd + bd) ----
__global__ __launch_bounds__(64) void k_final(const float* __restrict__ pool,
                                              const float* __restrict__ cntf,
                                              const float* __restrict__ wd,
                                              const float* __restrict__ bd,
                                              float* __restrict__ out) {
  int g = blockIdx.x;
  int t = threadIdx.x;
  float inv = 1.f / fmaxf(cntf[g], 1.f);
  float v = pool[(size_t)g * HH + t] * inv * wd[t] +
            pool[(size_t)g * HH + 64 + t] * inv * wd[64 + t];
#pragma unroll
  for (int d = 32; d; d >>= 1) v += __shfl_down(v, d);
  if (t == 0) out[g] = 1.f / (1.f + __expf(-(v + bd[0])));
}

// ---------------------------------------------------------------------------
extern "C" void kernel_launch(void* const* d_in, const int* in_sizes, int n_in,
                              void* d_out, int out_size, void* d_ws, size_t ws_size,
                              hipStream_t stream) {
  const float* x     = (const float*)d_in[0];
  const float* eattr = (const float*)d_in[1];
  const int*   eidx  = (const int*)d_in[2];
  const int*   batch = (const int*)d_in[3];
  const float* wn    = (const float*)d_in[4];
  const float* bnb   = (const float*)d_in[5];
  const float* we    = (const float*)d_in[6];
  const float* be    = (const float*)d_in[7];
  const float* cw1   = (const float*)d_in[8];
  const float* cb1   = (const float*)d_in[9];
  const float* cg    = (const float*)d_in[10];
  const float* cbt   = (const float*)d_in[11];
  const float* cw2   = (const float*)d_in[12];
  const float* cb2   = (const float*)d_in[13];
  const float* wd    = (const float*)d_in[14];
  const float* bd    = (const float*)d_in[15];
  float* out = (float*)d_out;

  const int N = in_sizes[0] / 6;
  const int E = in_sizes[1] / 4;
  const int G = out_size;

  const int* src = eidx;
  const int* dst = eidx + E;

  char* ws = (char*)d_ws;
  size_t off = 0;
  auto alloc = [&](size_t bytes) -> char* {
    char* p = ws + off;
    off = (off + bytes + 255) & ~(size_t)255;
    return p;
  };
  __half* h16    = (__half*)alloc((size_t)N * HH * 2);
  ushort* hresb  = (ushort*)alloc((size_t)N * HH * 2);
  ushort* h1b    = (ushort*)alloc((size_t)N * H2 * 2);
  int*    rowptr = (int*)alloc((size_t)(N + 1) * 4);
  int*    counts = (int*)alloc((size_t)N * 4);
  int*    fill   = (int*)alloc((size_t)N * 4);
  int*    ssrc   = (int*)alloc((size_t)E * 4);
  float4* eattrs = (float4*)alloc((size_t)E * 16);
  float*  stats  = (float*)alloc(512 * 4);
  float*  bnsc   = (float*)alloc(256 * 4);
  float*  bnsh   = (float*)alloc(256 * 4);
  float*  pool   = (float*)alloc((size_t)G * HH * 4);
  float*  cntf   = (float*)alloc((size_t)G * 4);
  short*  w1f    = (short*)alloc((size_t)3 * HH * H2 * 2);
  short*  w2f    = (short*)alloc((size_t)3 * H2 * HH * 2);

  (void)ws_size; (void)n_in;

  hipMemsetAsync(counts, 0, (size_t)N * 4, stream);
  hipMemsetAsync(fill, 0, (size_t)N * 4, stream);
  hipMemsetAsync(pool, 0, (size_t)G * HH * 4, stream);
  hipMemsetAsync(cntf, 0, (size_t)G * 4, stream);

  // weight pre-convert to fragment-major bf16 (all 3 layers)
  k_wconv<<<dim3(128, 3), 256, 0, stream>>>(cw1, w1f, 8, HH);   // [128][256]
  k_wconv<<<dim3(128, 3), 256, 0, stream>>>(cw2, w2f, 7, H2);   // [256][128]

  k_encode<<<(N + 1) / 2, 256, 0, stream>>>(x, wn, bnb, h16, N);
  k_hist<<<(E + 255) / 256, 256, 0, stream>>>(dst, counts, E);
  k_scan<<<1, 1024, 0, stream>>>(counts, rowptr, N);
  k_fill<<<(E + 255) / 256, 256, 0, stream>>>(src, dst, (const float4*)eattr,
                                              rowptr, fill, ssrc, eattrs, E);

  int mtiles = (N + 127) / 128;
  for (int layer = 0; layer < 3; ++layer) {
    const short* w1 = w1f + (size_t)layer * HH * H2;
    const float* b1 = cb1 + (size_t)layer * H2;
    const float* g_ = cg + (size_t)layer * H2;
    const float* bt = cbt + (size_t)layer * H2;
    const short* w2 = w2f + (size_t)layer * H2 * HH;
    const float* b2 = cb2 + (size_t)layer * HH;

    k_conv<<<N, 128, 0, stream>>>(h16, eattrs, we, be, rowptr, ssrc, hresb, N);
    hipMemsetAsync(stats, 0, 512 * 4, stream);
    k_mm1f<<<dim3(mtiles, 2), 256, 0, stream>>>(hresb, w1, b1, h1b, stats, stats + 256, N);
    k_bnfin<<<1, 256, 0, stream>>>(stats, stats + 256, g_, bt, bnsc, bnsh, 1.f / (float)N);
    k_mm2f<<<dim3(mtiles, 1), 256, 0, stream>>>(h1b, w2, b2, bnsc, bnsh, h16, N);
  }

  k_cnt<<<(N + 255) / 256, 256, 0, stream>>>(batch, cntf, N);
  k_pool<<<(N + 63) / 64, 128, 0, stream>>>(h16, batch, pool, N);
  k_final<<<G, 64, 0, stream>>>(pool, cntf, wd, bd, out);
}